// Round 3
// baseline (1176.053 us; speedup 1.0000x reference)
//
#include <hip/hip_runtime.h>
#include <stdint.h>

typedef unsigned short u16;
typedef __attribute__((ext_vector_type(8))) short short8;
typedef __attribute__((ext_vector_type(4))) float floatx4;

#define D_IN  512
#define M_TOT 24000
#define V_DIM 4000
#define V_PAD 4096
#define T_DIM 150
#define U_DIM 40

// dynamic LDS layout for k_fused
#define SMEM_A   16384            // A: [row 16][kch 64][8 u16], XOR-swizzled
#define SMEM_B   131072           // B: [wave 8][buf 2][frag 8][512 u16]
#define SMEM_SER 512
#define SMEM_TOT (SMEM_A + SMEM_B + SMEM_SER)

__device__ __forceinline__ u16 f2bf(float f) {
    union { float f; uint32_t u; } v; v.f = f;
    uint32_t r = v.u + 0x7FFF + ((v.u >> 16) & 1);   // RNE
    return (u16)(r >> 16);
}

__device__ __forceinline__ void gld_lds16(const u16* g, u16* l) {
    __builtin_amdgcn_global_load_lds(
        (const __attribute__((address_space(1))) void*)g,
        (__attribute__((address_space(3))) void*)l,
        16, 0, 0);
}

// ---------------------------------------------------------------------------
// Kernel 1: enc = enc_state @ W_enc^T + b_enc   [600,512]
//           dec = dec_state @ W_prd^T + b_prd   [160,512]
// ---------------------------------------------------------------------------
__global__ void k_pre(const float* __restrict__ enc_state, const float* __restrict__ dec_state,
                      const float* __restrict__ W_enc, const float* __restrict__ b_enc,
                      const float* __restrict__ W_prd, const float* __restrict__ b_prd,
                      float* __restrict__ enc_o, float* __restrict__ dec_o)
{
    const float* Ag; const float* Wg; const float* bg; float* Og; int M;
    int by = blockIdx.y;
    if (by < 19) { Ag = enc_state; Wg = W_enc; bg = b_enc; Og = enc_o; M = 600; }
    else         { Ag = dec_state; Wg = W_prd; bg = b_prd; Og = dec_o; M = 160; by -= 19; }

    const int row0 = by * 32;
    const int col0 = blockIdx.x * 64;
    __shared__ float Ash[32][17];
    __shared__ float Bsh[64][17];
    const int tid = threadIdx.x;
    const int tr = tid & 31;
    const int tc = tid >> 5;
    float accv[8] = {0.f,0.f,0.f,0.f,0.f,0.f,0.f,0.f};

    for (int k0 = 0; k0 < D_IN; k0 += 16) {
        __syncthreads();
        #pragma unroll
        for (int s = 0; s < 2; ++s) {
            int idx = tid + s * 256;
            int r = idx >> 4, c = idx & 15;
            Ash[r][c] = (row0 + r < M) ? Ag[(size_t)(row0 + r) * D_IN + k0 + c] : 0.f;
        }
        #pragma unroll
        for (int s = 0; s < 4; ++s) {
            int idx = tid + s * 256;
            int r = idx >> 4, c = idx & 15;
            Bsh[r][c] = Wg[(size_t)(col0 + r) * D_IN + k0 + c];
        }
        __syncthreads();
        #pragma unroll
        for (int kk = 0; kk < 16; ++kk) {
            float a = Ash[tr][kk];
            #pragma unroll
            for (int j = 0; j < 8; ++j) accv[j] += a * Bsh[tc * 8 + j][kk];
        }
    }
    if (row0 + tr < M) {
        #pragma unroll
        for (int j = 0; j < 8; ++j)
            Og[(size_t)(row0 + tr) * D_IN + col0 + tc * 8 + j] = accv[j] + bg[col0 + tc * 8 + j];
    }
}

// ---------------------------------------------------------------------------
// Kernel 2: W_proj [4000,512] fp32 -> bf16 [4096,512], zero pad rows.
// ---------------------------------------------------------------------------
__global__ void k_wconv(const float* __restrict__ W_proj, u16* __restrict__ Wp)
{
    int gid = blockIdx.x * 256 + threadIdx.x;
    int idx8 = gid * 8;
    int row = idx8 >> 9;
    short8 w;
    if (row < V_DIM) {
        const float* p = W_proj + idx8;
        #pragma unroll
        for (int j = 0; j < 8; ++j) w[j] = (short)f2bf(p[j]);
    } else {
        w = (short8){0,0,0,0,0,0,0,0};
    }
    *(short8*)&Wp[idx8] = w;
}

// ---------------------------------------------------------------------------
// Kernel 3: joint[m,i] = tanh(enc[b,t,i] + dec[b,u,i]) -> bf16 [24000,512]
// ---------------------------------------------------------------------------
__global__ void k_joint(const float* __restrict__ enc_o, const float* __restrict__ dec_o,
                        u16* __restrict__ J)
{
    int m = blockIdx.x * 4 + (threadIdx.x >> 6);
    int i = (threadIdx.x & 63) * 8;
    int b = m / (T_DIM * U_DIM);
    int r = m % (T_DIM * U_DIM);
    int t = r / U_DIM, u = r % U_DIM;
    const float4* e = (const float4*)(enc_o + (size_t)(b * T_DIM + t) * D_IN + i);
    const float4* d = (const float4*)(dec_o + (size_t)(b * U_DIM + u) * D_IN + i);
    float4 e0 = e[0], e1 = e[1], d0 = d[0], d1 = d[1];
    short8 w;
    w[0] = (short)f2bf(tanhf(e0.x + d0.x));
    w[1] = (short)f2bf(tanhf(e0.y + d0.y));
    w[2] = (short)f2bf(tanhf(e0.z + d0.z));
    w[3] = (short)f2bf(tanhf(e0.w + d0.w));
    w[4] = (short)f2bf(tanhf(e1.x + d1.x));
    w[5] = (short)f2bf(tanhf(e1.y + d1.y));
    w[6] = (short)f2bf(tanhf(e1.z + d1.z));
    w[7] = (short)f2bf(tanhf(e1.w + d1.w));
    *(short8*)&J[(size_t)m * D_IN + i] = w;
}

// ---------------------------------------------------------------------------
// Kernel 4 (fused GEMM + log-softmax), v3:
// Block owns 16 complete rows (4096 cols in regs), LSE in-register, single
// nontemporal C write. 8 waves x 512 cols.
// Engine rebuilt vs v2: no branch in K-loop (Wp pad rows are zero);
// B staged via global_load_lds into per-wave double-buffered LDS slices with
// counted vmcnt(8) waits (8 loads always in flight / wave); A-frags hoisted
// once into 64 VGPRs from an XOR-swizzled LDS tile (conflict-free).
// Reg budget: acc 128 + af 64 + bfr 32 + addr ~15 => ~240 <= 256, no spill.
// ---------------------------------------------------------------------------
__global__ __launch_bounds__(512, 2) void k_fused(const u16* __restrict__ J,
                                                  const u16* __restrict__ Bt,
                                                  const float* __restrict__ bias,
                                                  float* __restrict__ C)
{
    extern __shared__ char smem[];
    u16* Blds = (u16*)(smem + SMEM_A);                 // [wave][buf][frag][512]
    float (*sered)[16] = (float(*)[16])(smem + SMEM_A + SMEM_B);

    const int tid  = threadIdx.x;
    const int row0 = blockIdx.x * 16;                  // 1500 * 16 = 24000 exact
    const int wave = tid >> 6;
    const int lane = tid & 63;
    const int lrow = lane & 15;                        // A-row / B-row(=out col)
    const int lq   = lane >> 4;                        // k-quarter
    const int wc0  = wave << 9;                        // wave col base

    // ---- stage A: coalesced global read, XOR-swizzled LDS write ----
    // byte addr = row*1024 + ((kch*16) ^ ((row&7)<<4)) : writes conflict-free
    // (row uniform per wave, contiguous-permuted 1KB), reads 2-way (free).
    #pragma unroll
    for (int s = 0; s < 2; ++s) {
        int c = tid + s * 512;
        int row = c >> 6, kch = c & 63;
        short8 v = *(const short8*)(J + (size_t)(row0 + row) * D_IN + kch * 8);
        *(short8*)(smem + row * 1024 + ((kch * 16) ^ ((row & 7) << 4))) = v;
    }
    __syncthreads();

    // ---- hoist all 16 A-frags to registers (64 VGPR) ----
    short8 af[16];
    #pragma unroll
    for (int kk = 0; kk < 16; ++kk) {
        int kch = (kk << 2) + lq;
        af[kk] = *(const short8*)(smem + lrow * 1024 + ((kch * 16) ^ ((lrow & 7) << 4)));
    }

    floatx4 acc[32];
    #pragma unroll
    for (int ct = 0; ct < 32; ++ct) acc[ct] = (floatx4){0.f, 0.f, 0.f, 0.f};

    // per-lane global B address; per-wave LDS slice
    const u16* gw = Bt + (size_t)(wc0 + lrow) * D_IN + lq * 8;
    u16* Bw = Blds + wave * 8192;                      // 2 bufs x 4096 u16

    // ---- prologue: DMA steps 0 (buf0) and 1 (buf1) ----
    #pragma unroll
    for (int j = 0; j < 8; ++j) gld_lds16(gw + j * 32,       &Bw[j * 512]);
    #pragma unroll
    for (int j = 0; j < 8; ++j) gld_lds16(gw + 256 + j * 32, &Bw[4096 + j * 512]);

    // ---- main loop: 64 steps (32 tiles x 2 halves), 1-step lookahead ----
    #pragma unroll
    for (int ct = 0; ct < 32; ++ct) {
        #pragma unroll
        for (int h = 0; h < 2; ++h) {
            const int s = ct * 2 + h;
            u16* Bb = Bw + (s & 1) * 4096;
            // wait for DMA(s): only DMA(s+1)'s 8 may remain outstanding
            if (s == 63) asm volatile("s_waitcnt vmcnt(0)" ::: "memory");
            else         asm volatile("s_waitcnt vmcnt(8)" ::: "memory");
            short8 bfr[8];
            #pragma unroll
            for (int j = 0; j < 8; ++j)
                bfr[j] = *(const short8*)&Bb[j * 512 + lane * 8];
            // buffer free only when ds_reads retired; then reuse it for s+2
            asm volatile("s_waitcnt lgkmcnt(0)" ::: "memory");
            __builtin_amdgcn_sched_barrier(0);
            if (s + 2 < 64) {
                const u16* g = gw + ((s + 2) >> 1) * (16 * D_IN) + ((s + 2) & 1) * 256;
                #pragma unroll
                for (int j = 0; j < 8; ++j) gld_lds16(g + j * 32, &Bb[j * 512]);
            }
            #pragma unroll
            for (int j = 0; j < 8; ++j)
                acc[ct] = __builtin_amdgcn_mfma_f32_16x16x32_bf16(af[h * 8 + j], bfr[j], acc[ct], 0, 0, 0);
        }
    }

    // ---- epilogue: bias + per-lane exp-sums ----
    float se[4] = {0.f, 0.f, 0.f, 0.f};
    #pragma unroll
    for (int ct = 0; ct < 32; ++ct) {
        int cc = wc0 + ct * 16;
        if (cc < V_DIM) {
            float bv = bias[cc + lrow];
            #pragma unroll
            for (int r = 0; r < 4; ++r) {
                float lg = acc[ct][r] + bv;
                acc[ct][r] = lg;
                se[r] += __expf(lg);
            }
        }
    }
    #pragma unroll
    for (int m = 1; m < 16; m <<= 1) {
        #pragma unroll
        for (int r = 0; r < 4; ++r) se[r] += __shfl_xor(se[r], m, 64);
    }
    if (lrow == 0) {
        #pragma unroll
        for (int r = 0; r < 4; ++r) sered[wave][lq * 4 + r] = se[r];
    }
    __syncthreads();
    float lse[4];
    #pragma unroll
    for (int r = 0; r < 4; ++r) {
        float tot = 0.f;
        #pragma unroll
        for (int w = 0; w < 8; ++w) tot += sered[w][lq * 4 + r];
        lse[r] = __logf(tot);
    }

    // ---- single write of C (nontemporal) ----
    float* crow = C + (size_t)(row0 + lq * 4) * V_DIM + lrow;
    #pragma unroll
    for (int ct = 0; ct < 32; ++ct) {
        int cc = wc0 + ct * 16;
        if (cc < V_DIM) {
            #pragma unroll
            for (int r = 0; r < 4; ++r)
                __builtin_nontemporal_store(acc[ct][r] - lse[r], crow + (size_t)r * V_DIM + cc);
        }
    }
}

extern "C" void kernel_launch(void* const* d_in, const int* in_sizes, int n_in,
                              void* d_out, int out_size, void* d_ws, size_t ws_size,
                              hipStream_t stream)
{
    const float* enc_state = (const float*)d_in[0];
    const float* dec_state = (const float*)d_in[1];
    const float* W_enc     = (const float*)d_in[2];
    const float* b_enc     = (const float*)d_in[3];
    const float* W_prd     = (const float*)d_in[4];
    const float* b_prd     = (const float*)d_in[5];
    const float* W_proj    = (const float*)d_in[6];
    const float* b_proj    = (const float*)d_in[7];
    float* out = (float*)d_out;

    char* ws = (char*)d_ws;
    float* enc_o = (float*)(ws);                  // 1,228,800 B
    float* dec_o = (float*)(ws + 1228800);        //   327,680 B
    u16*   Wp    = (u16*)  (ws + 1556480);        // 4,194,304 B
    u16*   J     = (u16*)  (ws + 5750784);        // 24,576,000 B

    static int cfg = 0;
    if (!cfg) {
        hipFuncSetAttribute((const void*)k_fused,
                            hipFuncAttributeMaxDynamicSharedMemorySize, SMEM_TOT);
        cfg = 1;
    }

    k_pre  <<<dim3(8, 24), 256, 0, stream>>>(enc_state, dec_state, W_enc, b_enc, W_prd, b_prd, enc_o, dec_o);
    k_wconv<<<dim3(1024),  256, 0, stream>>>(W_proj, Wp);
    k_joint<<<dim3(6000),  256, 0, stream>>>(enc_o, dec_o, J);
    k_fused<<<dim3(1500),  512, SMEM_TOT, stream>>>(J, Wp, b_proj, out);
}